// Round 4
// baseline (644.287 us; speedup 1.0000x reference)
//
#include <hip/hip_runtime.h>
#include <cstdint>
#include <cstddef>

// ---------- types ----------
typedef __attribute__((ext_vector_type(8))) __bf16 bf16x8;
typedef __attribute__((ext_vector_type(4))) float f32x4;
typedef __attribute__((ext_vector_type(8))) unsigned short us8;
typedef __attribute__((ext_vector_type(4))) unsigned short us4;

__device__ inline unsigned short f2bf(float f) {
    unsigned int u = __float_as_uint(f);
    u += 0x7fffu + ((u >> 16) & 1u);   // RNE
    return (unsigned short)(u >> 16);
}

// pack two f32 -> two bf16 by truncation (1 instr); |rel err| < 2^-8, fine for P
__device__ inline unsigned int pkbf_t(float hi, float lo) {
    return __builtin_amdgcn_perm(__float_as_uint(hi), __float_as_uint(lo), 0x07060302u);
}

// LDS-visibility barrier WITHOUT vmcnt drain: in-flight global->VGPR prefetch
// loads survive across it (the compiler's __syncthreads would drain vmcnt(0)).
#define LDS_BARRIER() asm volatile("s_waitcnt lgkmcnt(0)\ns_barrier" ::: "memory")

// ---------- fp32 -> bf16 convert ----------
__global__ __launch_bounds__(256) void cvt_bf16(const float* __restrict__ in,
                                                unsigned short* __restrict__ out, int n4) {
    int i = blockIdx.x * 256 + threadIdx.x;
    if (i < n4) {
        float4 v = ((const float4*)in)[i];
        us4 o;
        o[0] = f2bf(v.x); o[1] = f2bf(v.y); o[2] = f2bf(v.z); o[3] = f2bf(v.w);
        ((us4*)out)[i] = o;
    }
}

// ---------- layernorm (fp32 in, bf16 out) ----------
__global__ __launch_bounds__(256) void ln_bf16(const float* __restrict__ X,
                                               const float* __restrict__ g,
                                               const float* __restrict__ b,
                                               unsigned short* __restrict__ out) {
    int row = blockIdx.x;
    int t = threadIdx.x;
    float4 v = ((const float4*)(X + (size_t)row * 1024))[t];
    float s  = v.x + v.y + v.z + v.w;
    float s2 = v.x * v.x + v.y * v.y + v.z * v.z + v.w * v.w;
#pragma unroll
    for (int m = 1; m < 64; m <<= 1) {
        s  += __shfl_xor(s, m, 64);
        s2 += __shfl_xor(s2, m, 64);
    }
    __shared__ float red[8];
    int w = t >> 6, l = t & 63;
    if (l == 0) { red[w] = s; red[4 + w] = s2; }
    __syncthreads();
    s  = red[0] + red[1] + red[2] + red[3];
    s2 = red[4] + red[5] + red[6] + red[7];
    float mu  = s * (1.0f / 1024.0f);
    float var = s2 * (1.0f / 1024.0f) - mu * mu;
    float rs  = rsqrtf(var + 1e-5f);
    int c = t * 4;
    float4 gv = *(const float4*)(g + c);
    float4 bv = *(const float4*)(b + c);
    us4 o;
    o[0] = f2bf((v.x - mu) * rs * gv.x + bv.x);
    o[1] = f2bf((v.y - mu) * rs * gv.y + bv.y);
    o[2] = f2bf((v.z - mu) * rs * gv.z + bv.z);
    o[3] = f2bf((v.w - mu) * rs * gv.w + bv.w);
    *(us4*)(out + (size_t)row * 1024 + c) = o;
}

// ---------- NT GEMM: C[M,N] = A[M,K] @ B[N,K]^T, bf16 in, fp32 acc ----------
// Register-prefetch double-buffered pipeline: global->VGPR 2 tiles ahead,
// ds_write 1 tile ahead, one lgkm-only barrier per tile (no vmcnt drain).
// EPI: 1 gelu(bias)->bf16 ; 2 bias+resid->fp32 ;
//      6 fused QKV: col block selects Q(scaled)/K(blocked)/V^T(blocked)
#define BM 128
#define BN 128
#define BK 32

template <int EPI>
__global__ __launch_bounds__(256) void gemm_nt(const unsigned short* __restrict__ A,
                                               const unsigned short* __restrict__ B,
                                               const float* __restrict__ bias,
                                               const float* __restrict__ resid,
                                               void* __restrict__ Cout, int N, int K) {
    __shared__ __align__(16) unsigned short As[2][BM * BK];
    __shared__ __align__(16) unsigned short Bs[2][BN * BK];
    const int tid = threadIdx.x;
    const int lane = tid & 63, w = tid >> 6;
    const int quad = lane >> 4, l16 = lane & 15;
    const int wr = w >> 1, wc = w & 1;
    const size_t bm = (size_t)blockIdx.y * BM;
    const size_t bn = (size_t)blockIdx.x * BN;

    const int e0 = tid * 8, e1 = (256 + tid) * 8;
    const int r0 = e0 >> 5, c0 = e0 & 31;
    const int r1 = e1 >> 5, c1 = e1 & 31;
    const unsigned short* A0 = A + (bm + r0) * K + c0;
    const unsigned short* A1 = A + (bm + r1) * K + c1;
    const unsigned short* Bp0 = B + (bn + r0) * K + c0;
    const unsigned short* Bp1 = B + (bn + r1) * K + c1;

    us8 pa0, pa1, pb0, pb1;
    auto ldg = [&](int k0) {
        pa0 = *(const us8*)(A0 + k0);
        pa1 = *(const us8*)(A1 + k0);
        pb0 = *(const us8*)(Bp0 + k0);
        pb1 = *(const us8*)(Bp1 + k0);
    };
    auto sts = [&](int buf) {
        *(us8*)&As[buf][e0] = pa0;
        *(us8*)&As[buf][e1] = pa1;
        *(us8*)&Bs[buf][e0] = pb0;
        *(us8*)&Bs[buf][e1] = pb1;
    };

    f32x4 acc[4][4];
#pragma unroll
    for (int i = 0; i < 4; i++)
#pragma unroll
        for (int j = 0; j < 4; j++) acc[i][j] = (f32x4){0.f, 0.f, 0.f, 0.f};

    ldg(0);
    sts(0);
    ldg(BK);
    LDS_BARRIER();

    const int nk = K / BK;
    for (int kt = 0; kt < nk; ++kt) {
        const int cur = kt & 1;
        bf16x8 af[4], bfr[4];
#pragma unroll
        for (int mt = 0; mt < 4; mt++)
            af[mt] = *(const bf16x8*)&As[cur][(wr * 64 + mt * 16 + l16) * BK + quad * 8];
#pragma unroll
        for (int nt = 0; nt < 4; nt++)
            bfr[nt] = *(const bf16x8*)&Bs[cur][(wc * 64 + nt * 16 + l16) * BK + quad * 8];
#pragma unroll
        for (int mt = 0; mt < 4; mt++)
#pragma unroll
            for (int nt = 0; nt < 4; nt++)
                acc[mt][nt] = __builtin_amdgcn_mfma_f32_16x16x32_bf16(af[mt], bfr[nt],
                                                                      acc[mt][nt], 0, 0, 0);
        if (kt + 1 < nk) {
            sts(cur ^ 1);                     // waits vmcnt for tile kt+1 regs only
            if (kt + 2 < nk) ldg((kt + 2) * BK);   // stays in flight across barrier
        }
        LDS_BARRIER();
    }

#pragma unroll
    for (int mt = 0; mt < 4; mt++) {
#pragma unroll
        for (int nt = 0; nt < 4; nt++) {
#pragma unroll
            for (int r = 0; r < 4; r++) {
                size_t row = bm + wr * 64 + mt * 16 + quad * 4 + r;
                size_t col = bn + wc * 64 + nt * 16 + l16;
                float v = acc[mt][nt][r] + bias[col];
                if (EPI == 1) {
                    v = 0.5f * v * (1.0f + erff(v * 0.70710678118654752f));
                    ((unsigned short*)Cout)[row * N + col] = f2bf(v);
                } else if (EPI == 2) {
                    ((float*)Cout)[row * N + col] = v + resid[row * N + col];
                } else if (EPI == 6) {
                    int sel = (int)(bn >> 10);
                    if (sel == 0) {
                        ((unsigned short*)Cout)[row * 1024 + col] =
                            f2bf(v * 0.18033688011112042f);  // 0.125*log2(e)
                    } else {
                        int key = (int)row & 2047;
                        int bh  = (((int)row >> 11) << 4) | (((int)col >> 6) & 15);
                        int dh  = (int)col & 63;
                        size_t addr;
                        if (sel == 1)
                            addr = 8388608 + (size_t)bh * 131072 +
                                   (size_t)(key >> 6) * 4096 + (size_t)(key & 63) * 64 +
                                   ((((dh >> 3) ^ (key & 7))) << 3) + (dh & 7);
                        else
                            addr = 16777216 + (size_t)bh * 131072 +
                                   (size_t)(key >> 6) * 4096 + (size_t)dh * 64 +
                                   (((((key >> 3) & 7) ^ (dh & 7))) << 3) + (key & 7);
                        ((unsigned short*)Cout)[addr] = f2bf(v);
                    }
                }
            }
        }
    }
}

// ---------- flash attention v4: register-prefetch pipeline + XCD swizzle ----------
// grid: 1024 blocks; swizzled so the 16 q-blocks of one (b,h) are consecutive
// on one XCD (K/V stay L2-hot). block = 256 = 4 waves; wave owns 32 queries.
// Q pre-scaled by 0.125*log2e -> exp2 domain, p = exp2(s), no max tracking.
__global__ __launch_bounds__(256) void attn_kernel(const unsigned short* __restrict__ Q,
                                                   const unsigned short* __restrict__ Kb,
                                                   const unsigned short* __restrict__ Vtb,
                                                   unsigned short* __restrict__ O) {
    const int i = blockIdx.x;
    const int xcd = i & 7, slot = i >> 3;
    const int bh   = xcd * 8 + (slot >> 4);
    const int qblk = slot & 15;
    const int b = bh >> 4, h = bh & 15;
    const int tid = threadIdx.x, lane = tid & 63, w = tid >> 6;
    const int quad = lane >> 4, l16 = lane & 15;
    const int sw = l16 & 7;

    __shared__ __align__(16) unsigned short smem[24576];   // 48 KB
    unsigned short* Ks  = smem;                 // [2][64 key][swz 64 dh]
    unsigned short* Vts = smem + 8192;          // [2][64 dh][swz 64 key]
    unsigned short* Psw = smem + 16384 + w * 2048;  // per-wave [32 q][swz 64 key]

    const size_t qrow0 = (size_t)b * 2048 + (size_t)qblk * 128 + w * 32;
    const int hcol = h * 64;

    bf16x8 qfr[2][2];
#pragma unroll
    for (int qf = 0; qf < 2; qf++)
#pragma unroll
        for (int kp = 0; kp < 2; kp++)
            qfr[qf][kp] = *(const bf16x8*)(Q + (qrow0 + qf * 16 + l16) * 1024 +
                                           hcol + kp * 32 + quad * 8);

    f32x4 acc[4][2];
#pragma unroll
    for (int df = 0; df < 4; df++)
#pragma unroll
        for (int qf = 0; qf < 2; qf++) acc[df][qf] = (f32x4){0.f, 0.f, 0.f, 0.f};
    float l_[2] = {0.f, 0.f};

    const unsigned short* kg0 = Kb  + (size_t)bh * 131072 + tid * 8;
    const unsigned short* kg1 = kg0 + 2048;
    const unsigned short* vg0 = Vtb + (size_t)bh * 131072 + tid * 8;
    const unsigned short* vg1 = vg0 + 2048;

    us8 rk0, rk1, rv0, rv1;
    auto ldg = [&](int kt) {
        rk0 = *(const us8*)(kg0 + kt * 4096);
        rk1 = *(const us8*)(kg1 + kt * 4096);
        rv0 = *(const us8*)(vg0 + kt * 4096);
        rv1 = *(const us8*)(vg1 + kt * 4096);
    };
    auto sts = [&](int buf) {
        *(us8*)&Ks[buf * 4096 + tid * 8]         = rk0;
        *(us8*)&Ks[buf * 4096 + 2048 + tid * 8]  = rk1;
        *(us8*)&Vts[buf * 4096 + tid * 8]        = rv0;
        *(us8*)&Vts[buf * 4096 + 2048 + tid * 8] = rv1;
    };

    ldg(0);
    sts(0);
    ldg(1);
    LDS_BARRIER();

    for (int kt = 0; kt < 32; ++kt) {
        const int cur = kt & 1;
        const unsigned short* Kc = &Ks[cur * 4096];
        const unsigned short* Vc = &Vts[cur * 4096];

        // S^T[64 key][32 q] = K Q^T
        f32x4 s[4][2];
#pragma unroll
        for (int mf = 0; mf < 4; mf++)
#pragma unroll
            for (int qf = 0; qf < 2; qf++) s[mf][qf] = (f32x4){0.f, 0.f, 0.f, 0.f};
#pragma unroll
        for (int kp = 0; kp < 2; kp++) {
#pragma unroll
            for (int mf = 0; mf < 4; mf++) {
                bf16x8 kf = *(const bf16x8*)&Kc[(mf * 16 + l16) * 64 +
                                                (((kp * 4 + quad) ^ sw) << 3)];
#pragma unroll
                for (int qf = 0; qf < 2; qf++)
                    s[mf][qf] = __builtin_amdgcn_mfma_f32_16x16x32_bf16(kf, qfr[qf][kp],
                                                                        s[mf][qf], 0, 0, 0);
            }
        }

        // p = exp2(s); in-lane row sums; trunc-pack into Psw
#pragma unroll
        for (int mf = 0; mf < 4; mf++)
#pragma unroll
            for (int qf = 0; qf < 2; qf++) {
                float e0 = exp2f(s[mf][qf][0]);
                float e1 = exp2f(s[mf][qf][1]);
                float e2 = exp2f(s[mf][qf][2]);
                float e3 = exp2f(s[mf][qf][3]);
                l_[qf] += (e0 + e1) + (e2 + e3);
                *(uint2*)&Psw[(qf * 16 + l16) * 64 +
                              (((mf * 2 + (quad >> 1)) ^ sw) << 3) + ((quad & 1) << 2)] =
                    make_uint2(pkbf_t(e1, e0), pkbf_t(e3, e2));
            }
        asm volatile("s_waitcnt lgkmcnt(0)" ::: "memory");

        // out^T[64 dh][32 q] += V^T P^T
#pragma unroll
        for (int kp = 0; kp < 2; kp++) {
            bf16x8 pf[2];
#pragma unroll
            for (int qf = 0; qf < 2; qf++)
                pf[qf] = *(const bf16x8*)&Psw[(qf * 16 + l16) * 64 +
                                              (((kp * 4 + quad) ^ sw) << 3)];
#pragma unroll
            for (int df = 0; df < 4; df++) {
                bf16x8 vf = *(const bf16x8*)&Vc[(df * 16 + l16) * 64 +
                                                (((kp * 4 + quad) ^ sw) << 3)];
#pragma unroll
                for (int qf = 0; qf < 2; qf++)
                    acc[df][qf] = __builtin_amdgcn_mfma_f32_16x16x32_bf16(vf, pf[qf],
                                                                          acc[df][qf], 0, 0, 0);
            }
        }

        if (kt + 1 < 32) {
            sts(cur ^ 1);                 // waits vmcnt for tile kt+1 regs only
            if (kt + 2 < 32) ldg(kt + 2); // in flight across barrier
        }
        LDS_BARRIER();
    }

    // final row-sum reduction across quads (keys split 4 ways)
#pragma unroll
    for (int qf = 0; qf < 2; qf++) {
        l_[qf] += __shfl_xor(l_[qf], 16, 64);
        l_[qf] += __shfl_xor(l_[qf], 32, 64);
    }

    // epilogue: normalize, transpose through LDS, coalesced bf16 store
    float inv[2] = {1.f / l_[0], 1.f / l_[1]};
    unsigned short* Ls = smem;   // [64 dh][128 q] stride 130
#pragma unroll
    for (int df = 0; df < 4; df++)
#pragma unroll
        for (int qf = 0; qf < 2; qf++)
#pragma unroll
            for (int r = 0; r < 4; r++) {
                int dh = df * 16 + quad * 4 + r;
                int q  = w * 32 + qf * 16 + l16;
                Ls[dh * 130 + q] =
                    (unsigned short)((__float_as_uint(acc[df][qf][r] * inv[qf]) + 0x8000u) >> 16);
            }
    LDS_BARRIER();
    int q = tid >> 1, dh0 = (tid & 1) * 32;
    size_t obase = ((size_t)b * 2048 + (size_t)qblk * 128 + q) * 1024 + hcol + dh0;
#pragma unroll
    for (int c = 0; c < 4; c++) {
        us8 o;
#pragma unroll
        for (int j = 0; j < 8; j++) o[j] = Ls[(dh0 + c * 8 + j) * 130 + q];
        *(us8*)(O + obase + c * 8) = o;
    }
}

// ---------- launch ----------
extern "C" void kernel_launch(void* const* d_in, const int* in_sizes, int n_in,
                              void* d_out, int out_size, void* d_ws, size_t ws_size,
                              hipStream_t stream) {
    const float* x     = (const float*)d_in[0];
    const float* ln1_g = (const float*)d_in[1];
    const float* ln1_b = (const float*)d_in[2];
    const float* ln2_g = (const float*)d_in[3];
    const float* ln2_b = (const float*)d_in[4];
    const float* wq = (const float*)d_in[5];
    const float* bq = (const float*)d_in[6];
    const float* wk = (const float*)d_in[7];
    const float* bk = (const float*)d_in[8];
    const float* wv = (const float*)d_in[9];
    const float* bv = (const float*)d_in[10];
    const float* wo = (const float*)d_in[11];
    const float* bo = (const float*)d_in[12];
    const float* w1 = (const float*)d_in[13];
    const float* b1 = (const float*)d_in[14];
    const float* w2 = (const float*)d_in[15];
    const float* b2 = (const float*)d_in[16];

    const size_t MB = 1u << 20;
    char* ws = (char*)d_ws;
    unsigned short* wqkvb = (unsigned short*)(ws + 0 * MB);   // [3072,1024] bf16
    unsigned short* wob  = (unsigned short*)(ws + 6 * MB);
    unsigned short* w1b  = (unsigned short*)(ws + 8 * MB);
    unsigned short* w2b  = (unsigned short*)(ws + 16 * MB);
    unsigned short* hb   = (unsigned short*)(ws + 24 * MB);   // LN1 out, later attn out
    unsigned short* qkvb = (unsigned short*)(ws + 40 * MB);   // Q | K-blocked | V^T-blocked
    unsigned short* qb   = qkvb;
    unsigned short* kblk = qkvb + 8388608;
    unsigned short* vtblk= qkvb + 16777216;
    float*          x1   = (float*)(ws + 56 * MB);            // overlays kblk+vtblk (dead)
    unsigned short* h2b  = (unsigned short*)(ws + 40 * MB);   // overlays qb (dead)
    unsigned short* ff1b = (unsigned short*)(ws + 88 * MB);   // 64 MB
    float*          bqkv = (float*)(ws + 151 * MB);           // [3072] fp32

    const int D = 1024, FF = 4096, Mrows = 8192;

    cvt_bf16<<<(D * D / 4 + 255) / 256, 256, 0, stream>>>(wq, wqkvb,             D * D / 4);
    cvt_bf16<<<(D * D / 4 + 255) / 256, 256, 0, stream>>>(wk, wqkvb + D * D,     D * D / 4);
    cvt_bf16<<<(D * D / 4 + 255) / 256, 256, 0, stream>>>(wv, wqkvb + 2 * D * D, D * D / 4);
    cvt_bf16<<<(D * D / 4 + 255) / 256, 256, 0, stream>>>(wo, wob, D * D / 4);
    cvt_bf16<<<(FF * D / 4 + 255) / 256, 256, 0, stream>>>(w1, w1b, FF * D / 4);
    cvt_bf16<<<(FF * D / 4 + 255) / 256, 256, 0, stream>>>(w2, w2b, FF * D / 4);

    hipMemcpyAsync(bqkv,         bq, D * sizeof(float), hipMemcpyDeviceToDevice, stream);
    hipMemcpyAsync(bqkv + D,     bk, D * sizeof(float), hipMemcpyDeviceToDevice, stream);
    hipMemcpyAsync(bqkv + 2 * D, bv, D * sizeof(float), hipMemcpyDeviceToDevice, stream);

    ln_bf16<<<Mrows, 256, 0, stream>>>(x, ln1_g, ln1_b, hb);

    dim3 gQKV(3 * D / BN, Mrows / BM);
    gemm_nt<6><<<gQKV, 256, 0, stream>>>(hb, wqkvb, bqkv, nullptr, qkvb, D, D);

    attn_kernel<<<1024, 256, 0, stream>>>(qb, kblk, vtblk, hb);

    dim3 gD(D / BN, Mrows / BM);
    gemm_nt<2><<<gD, 256, 0, stream>>>(hb, wob, bo, x, x1, D, D);           // O + resid

    ln_bf16<<<Mrows, 256, 0, stream>>>(x1, ln2_g, ln2_b, h2b);

    dim3 gFF(FF / BN, Mrows / BM);
    gemm_nt<1><<<gFF, 256, 0, stream>>>(h2b, w1b, b1, nullptr, ff1b, FF, D);  // FF1+gelu

    gemm_nt<2><<<gD, 256, 0, stream>>>(ff1b, w2b, b2, x1, (float*)d_out, D, FF);  // FF2
}